// Round 1
// baseline (860.309 us; speedup 1.0000x reference)
//
#include <hip/hip_runtime.h>
#include <cstdint>

#define ALPHA_C 0.15f
#define ONE_MINUS_ALPHA 0.85f
#define CLIP_C 5.0f
#define EPS_C 1e-6f
#define LN_EPS_C 1e-5f

#define Bb 4
#define Ss 4096
#define Dd 2048
#define Mtot (Bb * Ss)  // 16384

typedef __attribute__((ext_vector_type(8))) short bf16x8;
typedef __attribute__((ext_vector_type(4))) float f32x4;

__device__ __forceinline__ short f2bf(float f) {
  union { float f; uint32_t u; } v; v.f = f;
  uint32_t r = v.u + 0x7fffu + ((v.u >> 16) & 1u);  // RNE
  return (short)(r >> 16);
}
__device__ __forceinline__ float sigf(float x) { return 1.0f / (1.0f + __expf(-x)); }
__device__ __forceinline__ float geluf(float x) {
  const float c = 0.7978845608028654f;  // sqrt(2/pi)
  float x3 = x * x * x;
  return 0.5f * x * (1.0f + tanhf(c * (x + 0.044715f * x3)));
}

__device__ __forceinline__ void load_lds16(const short* g, short* l) {
  __builtin_amdgcn_global_load_lds((__attribute__((address_space(1))) void*)g,
                                   (__attribute__((address_space(3))) void*)l, 16, 0, 0);
}

// ---------------- GEMM: C[M,N] = A[M,K](bf16) * Bt[N,K](bf16)^T + bias ----------------
// MODE 0: C fp32 = v + bias. MODE 1: C bf16 = gelu(v + bias).
#define BM 128
#define BN 128
#define BK 32

template <int MODE>
__global__ __launch_bounds__(256, 2) void gemm_tn(
    const short* __restrict__ A, const short* __restrict__ Bt, void* __restrict__ Cout,
    const float* __restrict__ bias, int M, int N, int K) {
  __shared__ __align__(16) short As[BM * BK];
  __shared__ __align__(16) short Bs[BN * BK];

  const int tid = threadIdx.x;
  const int wave = tid >> 6;
  const int lane = tid & 63;
  const int quad = lane >> 4;
  const int l16 = lane & 15;
  const int m0 = blockIdx.y * BM;
  const int n0 = blockIdx.x * BN;
  const int wm = (wave & 1) * 64;
  const int wn = (wave >> 1) * 64;

  // staging: wave handles 32 rows of each tile, as two 16-row (1KB) chunks.
  // LDS layout: row-major [128][32] bf16, 64B/row; lane l writes row 16c + l/4, bytes (l%4)*16.
  const int srow = wave * 32 + (lane >> 2);
  const int skoff = (lane & 3) * 8;
  const short* agp = A + (long)(m0 + srow) * K + skoff;
  const short* bgp = Bt + (long)(n0 + srow) * K + skoff;
  const short* agp2 = agp + (long)16 * K;
  const short* bgp2 = bgp + (long)16 * K;
  short* al = As + (wave * 32) * BK;
  short* al2 = al + 16 * BK;
  short* bl = Bs + (wave * 32) * BK;
  short* bl2 = bl + 16 * BK;

  f32x4 acc[4][4] = {};

  for (int k0 = 0; k0 < K; k0 += BK) {
    __syncthreads();
    load_lds16(agp + k0, al);
    load_lds16(agp2 + k0, al2);
    load_lds16(bgp + k0, bl);
    load_lds16(bgp2 + k0, bl2);
    __syncthreads();

    bf16x8 af[4], bfr[4];
#pragma unroll
    for (int i = 0; i < 4; ++i)
      af[i] = *(const bf16x8*)&As[(wm + i * 16 + l16) * BK + quad * 8];
#pragma unroll
    for (int j = 0; j < 4; ++j)
      bfr[j] = *(const bf16x8*)&Bs[(wn + j * 16 + l16) * BK + quad * 8];
#pragma unroll
    for (int i = 0; i < 4; ++i)
#pragma unroll
      for (int j = 0; j < 4; ++j)
        acc[i][j] = __builtin_amdgcn_mfma_f32_16x16x32_bf16(af[i], bfr[j], acc[i][j], 0, 0, 0);
  }

#pragma unroll
  for (int i = 0; i < 4; ++i) {
#pragma unroll
    for (int r = 0; r < 4; ++r) {
      const int row = m0 + wm + i * 16 + quad * 4 + r;
      const long rb = (long)row * N;
#pragma unroll
      for (int j = 0; j < 4; ++j) {
        const int col = n0 + wn + j * 16 + l16;
        float v = acc[i][j][r] + bias[col];
        if (MODE == 0)
          ((float*)Cout)[rb + col] = v;
        else
          ((short*)Cout)[rb + col] = f2bf(geluf(v));
      }
    }
  }
}

// ---------------- elementwise / prep ----------------
__global__ __launch_bounds__(256) void cast_x_kernel(const float* __restrict__ in,
                                                     short* __restrict__ out, long n4) {
  long i = (long)blockIdx.x * blockDim.x + threadIdx.x;
  const long stride = (long)gridDim.x * blockDim.x;
  for (; i < n4; i += stride) {
    float4 v = ((const float4*)in)[i];
    short4 o;
    o.x = f2bf(v.x); o.y = f2bf(v.y); o.z = f2bf(v.z); o.w = f2bf(v.w);
    ((short4*)out)[i] = o;
  }
}

// in [R,C] fp32 -> out [C,R] bf16
__global__ __launch_bounds__(256) void tcast_kernel(const float* __restrict__ in,
                                                    short* __restrict__ out, int R, int C) {
  __shared__ float t[32][33];
  const int c0 = blockIdx.x * 32, r0 = blockIdx.y * 32;
  const int tx = threadIdx.x, ty = threadIdx.y;
#pragma unroll
  for (int i = 0; i < 32; i += 8)
    t[ty + i][tx] = in[(long)(r0 + ty + i) * C + (c0 + tx)];
  __syncthreads();
#pragma unroll
  for (int i = 0; i < 32; i += 8)
    out[(long)(c0 + ty + i) * R + (r0 + tx)] = f2bf(t[tx][ty + i]);
}

__global__ void pack_bias_kernel(const float* __restrict__ qb, const float* __restrict__ kb,
                                 float* __restrict__ o) {
  int i = threadIdx.x;
  o[i] = (i < 128) ? qb[i] : kb[i - 128];
}

// ---------------- EMA over time, segmented with warm-up ----------------
// score[b,t,f] = sig(qk[b,t,f]) * sig(qk[b,t,128+f]); ema[t] = a*s[t] + (1-a)*ema[t-1].
// 0.85^256 ~ 8e-19: a 256-step warm-up makes each 512-segment independent to fp32 exactness.
__global__ __launch_bounds__(128) void ema_kernel(const float* __restrict__ qk,
                                                  float* __restrict__ ema) {
  const int f = threadIdx.x;        // 0..127
  const int b = blockIdx.y;         // 0..3
  const int seg = blockIdx.x;       // 0..7
  const int t0 = seg * 512;
  const int tstart = (seg == 0) ? 0 : (t0 - 256);
  const int tend = t0 + 512;
  const float* __restrict__ base = qk + (long)b * Ss * 256;
  float* __restrict__ eb = ema + (long)b * Ss * 128;

  float e;
  {
    float q = base[(long)tstart * 256 + f];
    float k = base[(long)tstart * 256 + 128 + f];
    e = sigf(q) * sigf(k);
  }
  if (seg == 0) eb[f] = e;

  int t = tstart + 1;
  const int CH = 8;
  const int nch = (tend - t) / CH;
  float cur[CH];
#pragma unroll
  for (int i = 0; i < CH; ++i) {
    float q = base[(long)(t + i) * 256 + f];
    float k = base[(long)(t + i) * 256 + 128 + f];
    cur[i] = sigf(q) * sigf(k);
  }
  for (int c = 0; c < nch; ++c) {
    float nxt[CH] = {};
    if (c + 1 < nch) {
#pragma unroll
      for (int i = 0; i < CH; ++i) {
        float q = base[(long)(t + CH + i) * 256 + f];
        float k = base[(long)(t + CH + i) * 256 + 128 + f];
        nxt[i] = sigf(q) * sigf(k);
      }
    }
#pragma unroll
    for (int i = 0; i < CH; ++i) {
      e = fmaf(ALPHA_C, cur[i], ONE_MINUS_ALPHA * e);
      const int tt = t + i;
      if (tt >= t0) eb[(long)tt * 128 + f] = e;
    }
#pragma unroll
    for (int i = 0; i < CH; ++i) cur[i] = nxt[i];
    t += CH;
  }
  for (; t < tend; ++t) {
    float q = base[(long)t * 256 + f];
    float k = base[(long)t * 256 + 128 + f];
    float s = sigf(q) * sigf(k);
    e = fmaf(ALPHA_C, s, ONE_MINUS_ALPHA * e);
    if (t >= t0) eb[(long)t * 128 + f] = e;
  }
}

// per row: mean over 128, clip(ema/denom), * V, -> bf16
__global__ __launch_bounds__(256) void comb_kernel(const float* __restrict__ ema,
                                                   const float* __restrict__ V,
                                                   short* __restrict__ xcomb) {
  const int wv = threadIdx.x >> 6;
  const int lane = threadIdx.x & 63;
  const long row = (long)blockIdx.x * 4 + wv;
  const float* er = ema + row * 128;
  float e0 = er[lane], e1 = er[lane + 64];
  float s = e0 + e1;
#pragma unroll
  for (int m = 1; m < 64; m <<= 1) s += __shfl_xor(s, m, 64);
  const float denom = fmaxf(s * (1.0f / 128.0f), EPS_C);
  const float inv = 1.0f / denom;
  const float c0 = fminf(fmaxf(e0 * inv, -CLIP_C), CLIP_C);
  const float c1 = fminf(fmaxf(e1 * inv, -CLIP_C), CLIP_C);
  const float* vr = V + row * 128;
  xcomb[row * 128 + lane] = f2bf(c0 * vr[lane]);
  xcomb[row * 128 + 64 + lane] = f2bf(c1 * vr[lane + 64]);
}

// gated[r,i] = silu(out4[r,i]) * out4[r,1024+i], bf16
__global__ __launch_bounds__(256) void gate_kernel(const float* __restrict__ out4,
                                                   short* __restrict__ gated) {
  const long g = (long)blockIdx.x * 256 + threadIdx.x;  // one per 4 elems
  const long r = g >> 8;
  const int i4 = (int)(g & 255) * 4;
  const float4 a = *(const float4*)&out4[r * 2048 + i4];
  const float4 b = *(const float4*)&out4[r * 2048 + 1024 + i4];
  short4 o;
  o.x = f2bf(a.x * sigf(a.x) * b.x);
  o.y = f2bf(a.y * sigf(a.y) * b.y);
  o.z = f2bf(a.z * sigf(a.z) * b.z);
  o.w = f2bf(a.w * sigf(a.w) * b.w);
  *(short4*)&gated[r * 1024 + i4] = o;
}

// in-place: io = LN(io + x) * gamma + beta, row = 2048
__global__ __launch_bounds__(256) void ln_kernel(float* __restrict__ io,
                                                 const float* __restrict__ x,
                                                 const float* __restrict__ gamma,
                                                 const float* __restrict__ beta) {
  const long row = blockIdx.x;
  const int tid = threadIdx.x;
  const int wv = tid >> 6, lane = tid & 63;
  float* rp = io + row * 2048;
  const float* xp = x + row * 2048;
  float4 v0 = ((const float4*)rp)[tid * 2];
  float4 v1 = ((const float4*)rp)[tid * 2 + 1];
  float4 x0 = ((const float4*)xp)[tid * 2];
  float4 x1 = ((const float4*)xp)[tid * 2 + 1];
  float h[8] = {v0.x + x0.x, v0.y + x0.y, v0.z + x0.z, v0.w + x0.w,
                v1.x + x1.x, v1.y + x1.y, v1.z + x1.z, v1.w + x1.w};
  float sum = 0.f, ss = 0.f;
#pragma unroll
  for (int i = 0; i < 8; ++i) { sum += h[i]; ss += h[i] * h[i]; }
#pragma unroll
  for (int m = 1; m < 64; m <<= 1) {
    sum += __shfl_xor(sum, m, 64);
    ss += __shfl_xor(ss, m, 64);
  }
  __shared__ float rs[4], rq[4];
  if (lane == 0) { rs[wv] = sum; rq[wv] = ss; }
  __syncthreads();
  sum = rs[0] + rs[1] + rs[2] + rs[3];
  ss = rq[0] + rq[1] + rq[2] + rq[3];
  const float mu = sum * (1.0f / 2048.0f);
  const float var = ss * (1.0f / 2048.0f) - mu * mu;
  const float rstd = rsqrtf(var + LN_EPS_C);
  const int c0 = tid * 8;
  float o[8];
#pragma unroll
  for (int i = 0; i < 8; ++i)
    o[i] = (h[i] - mu) * rstd * gamma[c0 + i] + beta[c0 + i];
  ((float4*)rp)[tid * 2]     = make_float4(o[0], o[1], o[2], o[3]);
  ((float4*)rp)[tid * 2 + 1] = make_float4(o[4], o[5], o[6], o[7]);
}

// ---------------- launch ----------------
extern "C" void kernel_launch(void* const* d_in, const int* in_sizes, int n_in,
                              void* d_out, int out_size, void* d_ws, size_t ws_size,
                              hipStream_t stream) {
  const float* x         = (const float*)d_in[0];
  const float* Q_w       = (const float*)d_in[1];
  const float* Q_b       = (const float*)d_in[2];
  const float* K_w       = (const float*)d_in[3];
  const float* K_b       = (const float*)d_in[4];
  const float* lo_proj_w = (const float*)d_in[5];
  const float* lo_proj_b = (const float*)d_in[6];
  const float* lo_p_w    = (const float*)d_in[7];
  const float* lo_p_b    = (const float*)d_in[8];
  const float* proj_w    = (const float*)d_in[9];
  const float* proj_b    = (const float*)d_in[10];
  const float* O_w       = (const float*)d_in[11];
  const float* O_b       = (const float*)d_in[12];
  const float* ln_g      = (const float*)d_in[13];
  const float* ln_b      = (const float*)d_in[14];

  char* ws = (char*)d_ws;
  size_t off = 0;
  auto alloc = [&](size_t bytes) {
    char* p = ws + off;
    off += (bytes + 255) & ~(size_t)255;
    return p;
  };
  short* x16   = (short*)alloc((size_t)Mtot * Dd * 2);     // x bf16
  short* h16   = (short*)alloc((size_t)Mtot * Dd * 2);     // gelu hidden bf16
  float* qk    = (float*)alloc((size_t)Mtot * 256 * 4);    // [q|k] fp32
  float* vbuf  = (float*)alloc((size_t)Mtot * 128 * 4);    // V fp32
  float* emab  = (float*)alloc((size_t)Mtot * 128 * 4);    // ema fp32
  short* xcomb = (short*)alloc((size_t)Mtot * 128 * 2);    // bf16
  short* gated = (short*)alloc((size_t)Mtot * 1024 * 2);   // bf16
  short* wqkt  = (short*)alloc((size_t)256 * 2048 * 2);    // [Qw;Kw]^T bf16 [256,2048]
  short* lprjt = (short*)alloc((size_t)2048 * 2048 * 2);   // lo_proj^T
  short* lpt   = (short*)alloc((size_t)128 * 2048 * 2);    // lo_p^T
  short* prjt  = (short*)alloc((size_t)2048 * 128 * 2);    // proj^T
  short* ot    = (short*)alloc((size_t)2048 * 1024 * 2);   // O^T
  float* qkb   = (float*)alloc(256 * 4);
  float* outf  = (float*)d_out;  // doubles as fp32 [16384,2048] scratch for out4/out5

  cast_x_kernel<<<8192, 256, 0, stream>>>(x, x16, (long)Mtot * Dd / 4);
  tcast_kernel<<<dim3(4, 64), dim3(32, 8), 0, stream>>>(Q_w, wqkt, 2048, 128);
  tcast_kernel<<<dim3(4, 64), dim3(32, 8), 0, stream>>>(K_w, wqkt + 128 * 2048, 2048, 128);
  tcast_kernel<<<dim3(64, 64), dim3(32, 8), 0, stream>>>(lo_proj_w, lprjt, 2048, 2048);
  tcast_kernel<<<dim3(4, 64), dim3(32, 8), 0, stream>>>(lo_p_w, lpt, 2048, 128);
  tcast_kernel<<<dim3(64, 4), dim3(32, 8), 0, stream>>>(proj_w, prjt, 128, 2048);
  tcast_kernel<<<dim3(64, 32), dim3(32, 8), 0, stream>>>(O_w, ot, 1024, 2048);
  pack_bias_kernel<<<1, 256, 0, stream>>>(Q_b, K_b, qkb);

  // q|k = x @ [Qw|Kw] + [Qb|Kb]
  gemm_tn<0><<<dim3(2, 128), 256, 0, stream>>>(x16, wqkt, qk, qkb, Mtot, 256, 2048);
  // h = gelu(x @ lo_proj + b)  (bf16 out)
  gemm_tn<1><<<dim3(16, 128), 256, 0, stream>>>(x16, lprjt, h16, lo_proj_b, Mtot, 2048, 2048);
  // V = h @ lo_p + b
  gemm_tn<0><<<dim3(1, 128), 256, 0, stream>>>(h16, lpt, vbuf, lo_p_b, Mtot, 128, 2048);
  // score -> ema (segmented scan)
  ema_kernel<<<dim3(8, 4), 128, 0, stream>>>(qk, emab);
  // mean/clip * V -> x_comb bf16
  comb_kernel<<<Mtot / 4, 256, 0, stream>>>(emab, vbuf, xcomb);
  // out4 = x_comb @ proj + b   (fp32 into d_out)
  gemm_tn<0><<<dim3(16, 128), 256, 0, stream>>>(xcomb, prjt, outf, proj_b, Mtot, 2048, 128);
  // gated = silu(a)*b  -> bf16
  gate_kernel<<<16384, 256, 0, stream>>>(outf, gated);
  // out5 = gated @ O + b  (fp32 into d_out)
  gemm_tn<0><<<dim3(16, 128), 256, 0, stream>>>(gated, ot, outf, O_b, Mtot, 2048, 1024);
  // LN(out5 + x) in place
  ln_kernel<<<Mtot, 256, 0, stream>>>(outf, x, ln_g, ln_b);
}

// Round 2
// 749.433 us; speedup vs baseline: 1.1479x; 1.1479x over previous
//
#include <hip/hip_runtime.h>
#include <cstdint>

#define ALPHA_C 0.15f
#define ONE_MINUS_ALPHA 0.85f
#define CLIP_C 5.0f
#define EPS_C 1e-6f
#define LN_EPS_C 1e-5f

#define Bb 4
#define Ss 4096
#define Dd 2048
#define Mtot (Bb * Ss)  // 16384

typedef __attribute__((ext_vector_type(8))) short bf16x8;
typedef __attribute__((ext_vector_type(4))) float f32x4;

__device__ __forceinline__ short f2bf(float f) {
  union { float f; uint32_t u; } v; v.f = f;
  uint32_t r = v.u + 0x7fffu + ((v.u >> 16) & 1u);  // RNE
  return (short)(r >> 16);
}
__device__ __forceinline__ float bf2f(short s) {
  union { uint32_t u; float f; } v; v.u = ((uint32_t)(uint16_t)s) << 16;
  return v.f;
}
__device__ __forceinline__ float sigf(float x) { return 1.0f / (1.0f + __expf(-x)); }
__device__ __forceinline__ float geluf(float x) {
  const float c = 0.7978845608028654f;  // sqrt(2/pi)
  float x3 = x * x * x;
  return 0.5f * x * (1.0f + tanhf(c * (x + 0.044715f * x3)));
}

__device__ __forceinline__ void load_lds16(const short* g, short* l) {
  __builtin_amdgcn_global_load_lds((__attribute__((address_space(1))) void*)g,
                                   (__attribute__((address_space(3))) void*)l, 16, 0, 0);
}

// ---------------- GEMM: C[M,N] = A[M,K](bf16) * Bt[N,K](bf16)^T + bias ----------------
// MODE 0: out0 fp32 = v + bias.
// MODE 1: out0 bf16 = gelu(v + bias).
// MODE 2: out0 bf16 = v + bias.
// MODE 3: col<256 -> out0 fp32 (stride 256); else out1 bf16 gelu (stride 2048, col-256).
// LDS k-chunk XOR swizzle: LDS[row][c'] holds global chunk c' ^ ((row>>1)&3).
// -> fragment ds_read_b128 lands uniform 2-way on banks (free, m136) instead of 8-way.
#define BM 128
#define BN 128
#define BK 32

template <int MODE>
__global__ __launch_bounds__(256, 2) void gemm_tn(
    const short* __restrict__ A, const short* __restrict__ Bt, void* __restrict__ out0,
    void* __restrict__ out1, const float* __restrict__ bias, int M, int N, int K) {
  __shared__ __align__(16) short As[BM * BK];
  __shared__ __align__(16) short Bs[BN * BK];

  const int tid = threadIdx.x;
  const int wave = tid >> 6;
  const int lane = tid & 63;
  const int quad = lane >> 4;
  const int l16 = lane & 15;
  const int m0 = blockIdx.y * BM;
  const int n0 = blockIdx.x * BN;
  const int wm = (wave & 1) * 64;
  const int wn = (wave >> 1) * 64;

  // staging: wave stages 32 rows of each tile as two 16-row (1KB) chunks.
  // lane l -> row (l>>2), LDS chunk (l&3); global k-chunk = (l&3) ^ ((l>>3)&3).
  const int srow = wave * 32 + (lane >> 2);
  const int skoff = ((lane & 3) ^ ((lane >> 3) & 3)) * 8;
  const short* agp = A + (long)(m0 + srow) * K + skoff;
  const short* bgp = Bt + (long)(n0 + srow) * K + skoff;
  const short* agp2 = agp + (long)16 * K;
  const short* bgp2 = bgp + (long)16 * K;
  short* al = As + (wave * 32) * BK;
  short* al2 = al + 16 * BK;
  short* bl = Bs + (wave * 32) * BK;
  short* bl2 = bl + 16 * BK;

  const int rsw = (l16 >> 1) & 3;  // read-side swizzle key, depends only on row&15

  f32x4 acc[4][4] = {};

  for (int k0 = 0; k0 < K; k0 += BK) {
    __syncthreads();
    load_lds16(agp + k0, al);
    load_lds16(agp2 + k0, al2);
    load_lds16(bgp + k0, bl);
    load_lds16(bgp2 + k0, bl2);
    __syncthreads();

    bf16x8 af[4], bfr[4];
#pragma unroll
    for (int i = 0; i < 4; ++i)
      af[i] = *(const bf16x8*)&As[(wm + i * 16 + l16) * BK + (quad ^ rsw) * 8];
#pragma unroll
    for (int j = 0; j < 4; ++j)
      bfr[j] = *(const bf16x8*)&Bs[(wn + j * 16 + l16) * BK + (quad ^ rsw) * 8];
#pragma unroll
    for (int i = 0; i < 4; ++i)
#pragma unroll
      for (int j = 0; j < 4; ++j)
        acc[i][j] = __builtin_amdgcn_mfma_f32_16x16x32_bf16(af[i], bfr[j], acc[i][j], 0, 0, 0);
  }

#pragma unroll
  for (int i = 0; i < 4; ++i) {
#pragma unroll
    for (int r = 0; r < 4; ++r) {
      const int row = m0 + wm + i * 16 + quad * 4 + r;
#pragma unroll
      for (int j = 0; j < 4; ++j) {
        const int col = n0 + wn + j * 16 + l16;
        float v = acc[i][j][r] + bias[col];
        if (MODE == 0) {
          ((float*)out0)[(long)row * N + col] = v;
        } else if (MODE == 1) {
          ((short*)out0)[(long)row * N + col] = f2bf(geluf(v));
        } else if (MODE == 2) {
          ((short*)out0)[(long)row * N + col] = f2bf(v);
        } else {  // MODE 3: block-uniform branch (boundary 256 is tile-aligned)
          if (n0 < 256)
            ((float*)out0)[(long)row * 256 + col] = v;
          else
            ((short*)out1)[(long)row * 2048 + (col - 256)] = f2bf(geluf(v));
        }
      }
    }
  }
}

// ---------------- elementwise / prep ----------------
__global__ __launch_bounds__(256) void cast_x_kernel(const float* __restrict__ in,
                                                     short* __restrict__ out, long n4) {
  long i = (long)blockIdx.x * blockDim.x + threadIdx.x;
  const long stride = (long)gridDim.x * blockDim.x;
  for (; i < n4; i += stride) {
    float4 v = ((const float4*)in)[i];
    short4 o;
    o.x = f2bf(v.x); o.y = f2bf(v.y); o.z = f2bf(v.z); o.w = f2bf(v.w);
    ((short4*)out)[i] = o;
  }
}

// in [R,C] fp32 -> out [C,R] bf16
__global__ __launch_bounds__(256) void tcast_kernel(const float* __restrict__ in,
                                                    short* __restrict__ out, int R, int C) {
  __shared__ float t[32][33];
  const int c0 = blockIdx.x * 32, r0 = blockIdx.y * 32;
  const int tx = threadIdx.x, ty = threadIdx.y;
#pragma unroll
  for (int i = 0; i < 32; i += 8)
    t[ty + i][tx] = in[(long)(r0 + ty + i) * C + (c0 + tx)];
  __syncthreads();
#pragma unroll
  for (int i = 0; i < 32; i += 8)
    out[(long)(c0 + ty + i) * R + (r0 + tx)] = f2bf(t[tx][ty + i]);
}

// packed bias [Q_b(128); K_b(128); lo_proj_b(2048)]
__global__ void pack_bias_kernel(const float* __restrict__ qb, const float* __restrict__ kb,
                                 const float* __restrict__ lob, float* __restrict__ o) {
  int i = blockIdx.x * 256 + threadIdx.x;
  if (i < 128) o[i] = qb[i];
  else if (i < 256) o[i] = kb[i - 128];
  else if (i < 2304) o[i] = lob[i - 256];
}

// ---------------- EMA over time, short segments with warm-up ----------------
// ema[t]=0.15*s[t]+0.85*ema[t-1]; 0.85^96=1.7e-7 -> 96-step warm-up makes 64-long
// segments independent far below bf16 noise. 64 segs x 4 batches = 256 blocks.
#define SEG 64
#define WARM 96
__global__ __launch_bounds__(128) void ema_kernel(const float* __restrict__ qk,
                                                  float* __restrict__ ema) {
  const int f = threadIdx.x;        // 0..127
  const int b = blockIdx.y;         // 0..3
  const int seg = blockIdx.x;       // 0..63
  const int t0 = seg * SEG;
  const int tstart = (t0 >= WARM) ? (t0 - WARM) : 0;
  const int tend = t0 + SEG;
  const float* __restrict__ base = qk + (long)b * Ss * 256;
  float* __restrict__ eb = ema + (long)b * Ss * 128;

  float e;
  {
    float q = base[(long)tstart * 256 + f];
    float k = base[(long)tstart * 256 + 128 + f];
    e = sigf(q) * sigf(k);
  }
  if (seg == 0) eb[f] = e;

  int t = tstart + 1;
  const int CH = 8;
  const int nch = (tend - t) / CH;
  float cur[CH];
#pragma unroll
  for (int i = 0; i < CH; ++i) {
    float q = base[(long)(t + i) * 256 + f];
    float k = base[(long)(t + i) * 256 + 128 + f];
    cur[i] = ALPHA_C * (sigf(q) * sigf(k));
  }
  for (int c = 0; c < nch; ++c) {
    float nxt[CH] = {};
    if (c + 1 < nch) {
#pragma unroll
      for (int i = 0; i < CH; ++i) {
        float q = base[(long)(t + CH + i) * 256 + f];
        float k = base[(long)(t + CH + i) * 256 + 128 + f];
        nxt[i] = ALPHA_C * (sigf(q) * sigf(k));
      }
    }
#pragma unroll
    for (int i = 0; i < CH; ++i) {
      e = fmaf(ONE_MINUS_ALPHA, e, cur[i]);  // 1-fma dependent chain
      const int tt = t + i;
      if (tt >= t0) eb[(long)tt * 128 + f] = e;
    }
#pragma unroll
    for (int i = 0; i < CH; ++i) cur[i] = nxt[i];
    t += CH;
  }
  for (; t < tend; ++t) {
    float q = base[(long)t * 256 + f];
    float k = base[(long)t * 256 + 128 + f];
    e = fmaf(ONE_MINUS_ALPHA, e, ALPHA_C * (sigf(q) * sigf(k)));
    if (t >= t0) eb[(long)t * 128 + f] = e;
  }
}

// per row: mean over 128, clip(ema/denom), * V, -> bf16
__global__ __launch_bounds__(256) void comb_kernel(const float* __restrict__ ema,
                                                   const float* __restrict__ V,
                                                   short* __restrict__ xcomb) {
  const int wv = threadIdx.x >> 6;
  const int lane = threadIdx.x & 63;
  const long row = (long)blockIdx.x * 4 + wv;
  const float* er = ema + row * 128;
  float e0 = er[lane], e1 = er[lane + 64];
  float s = e0 + e1;
#pragma unroll
  for (int m = 1; m < 64; m <<= 1) s += __shfl_xor(s, m, 64);
  const float denom = fmaxf(s * (1.0f / 128.0f), EPS_C);
  const float inv = 1.0f / denom;
  const float c0 = fminf(fmaxf(e0 * inv, -CLIP_C), CLIP_C);
  const float c1 = fminf(fmaxf(e1 * inv, -CLIP_C), CLIP_C);
  const float* vr = V + row * 128;
  xcomb[row * 128 + lane] = f2bf(c0 * vr[lane]);
  xcomb[row * 128 + 64 + lane] = f2bf(c1 * vr[lane + 64]);
}

// gated[r,i] = silu(out4[r,i]) * out4[r,1024+i], bf16 in, bf16 out
__global__ __launch_bounds__(256) void gate_kernel(const short* __restrict__ out4,
                                                   short* __restrict__ gated) {
  const long g = (long)blockIdx.x * 256 + threadIdx.x;  // one per 4 elems
  const long r = g >> 8;
  const int i4 = (int)(g & 255) * 4;
  const short4 a4 = *(const short4*)&out4[r * 2048 + i4];
  const short4 b4 = *(const short4*)&out4[r * 2048 + 1024 + i4];
  float ax = bf2f(a4.x), ay = bf2f(a4.y), az = bf2f(a4.z), aw = bf2f(a4.w);
  short4 o;
  o.x = f2bf(ax * sigf(ax) * bf2f(b4.x));
  o.y = f2bf(ay * sigf(ay) * bf2f(b4.y));
  o.z = f2bf(az * sigf(az) * bf2f(b4.z));
  o.w = f2bf(aw * sigf(aw) * bf2f(b4.w));
  *(short4*)&gated[r * 1024 + i4] = o;
}

// in-place: io = LN(io + x) * gamma + beta, row = 2048
__global__ __launch_bounds__(256) void ln_kernel(float* __restrict__ io,
                                                 const float* __restrict__ x,
                                                 const float* __restrict__ gamma,
                                                 const float* __restrict__ beta) {
  const long row = blockIdx.x;
  const int tid = threadIdx.x;
  const int wv = tid >> 6, lane = tid & 63;
  float* rp = io + row * 2048;
  const float* xp = x + row * 2048;
  float4 v0 = ((const float4*)rp)[tid * 2];
  float4 v1 = ((const float4*)rp)[tid * 2 + 1];
  float4 x0 = ((const float4*)xp)[tid * 2];
  float4 x1 = ((const float4*)xp)[tid * 2 + 1];
  float h[8] = {v0.x + x0.x, v0.y + x0.y, v0.z + x0.z, v0.w + x0.w,
                v1.x + x1.x, v1.y + x1.y, v1.z + x1.z, v1.w + x1.w};
  float sum = 0.f, ss = 0.f;
#pragma unroll
  for (int i = 0; i < 8; ++i) { sum += h[i]; ss += h[i] * h[i]; }
#pragma unroll
  for (int m = 1; m < 64; m <<= 1) {
    sum += __shfl_xor(sum, m, 64);
    ss += __shfl_xor(ss, m, 64);
  }
  __shared__ float rs[4], rq[4];
  if (lane == 0) { rs[wv] = sum; rq[wv] = ss; }
  __syncthreads();
  sum = rs[0] + rs[1] + rs[2] + rs[3];
  ss = rq[0] + rq[1] + rq[2] + rq[3];
  const float mu = sum * (1.0f / 2048.0f);
  const float var = ss * (1.0f / 2048.0f) - mu * mu;
  const float rstd = rsqrtf(var + LN_EPS_C);
  const int c0 = tid * 8;
  float o[8];
#pragma unroll
  for (int i = 0; i < 8; ++i)
    o[i] = (h[i] - mu) * rstd * gamma[c0 + i] + beta[c0 + i];
  ((float4*)rp)[tid * 2]     = make_float4(o[0], o[1], o[2], o[3]);
  ((float4*)rp)[tid * 2 + 1] = make_float4(o[4], o[5], o[6], o[7]);
}

// ---------------- launch ----------------
extern "C" void kernel_launch(void* const* d_in, const int* in_sizes, int n_in,
                              void* d_out, int out_size, void* d_ws, size_t ws_size,
                              hipStream_t stream) {
  const float* x         = (const float*)d_in[0];
  const float* Q_w       = (const float*)d_in[1];
  const float* Q_b       = (const float*)d_in[2];
  const float* K_w       = (const float*)d_in[3];
  const float* K_b       = (const float*)d_in[4];
  const float* lo_proj_w = (const float*)d_in[5];
  const float* lo_proj_b = (const float*)d_in[6];
  const float* lo_p_w    = (const float*)d_in[7];
  const float* lo_p_b    = (const float*)d_in[8];
  const float* proj_w    = (const float*)d_in[9];
  const float* proj_b    = (const float*)d_in[10];
  const float* O_w       = (const float*)d_in[11];
  const float* O_b       = (const float*)d_in[12];
  const float* ln_g      = (const float*)d_in[13];
  const float* ln_b      = (const float*)d_in[14];

  char* ws = (char*)d_ws;
  size_t off = 0;
  auto alloc = [&](size_t bytes) {
    char* p = ws + off;
    off += (bytes + 255) & ~(size_t)255;
    return p;
  };
  short* x16   = (short*)alloc((size_t)Mtot * Dd * 2);      // x bf16
  short* h16   = (short*)alloc((size_t)Mtot * Dd * 2);      // gelu hidden bf16
  float* qk    = (float*)alloc((size_t)Mtot * 256 * 4);     // [q|k] fp32
  float* vbuf  = (float*)alloc((size_t)Mtot * 128 * 4);     // V fp32
  float* emab  = (float*)alloc((size_t)Mtot * 128 * 4);     // ema fp32
  short* xcomb = (short*)alloc((size_t)Mtot * 128 * 2);     // bf16
  short* gated = (short*)alloc((size_t)Mtot * 1024 * 2);    // bf16
  short* wbig  = (short*)alloc((size_t)2304 * 2048 * 2);    // [Qw;Kw;lo_proj]^T bf16 [2304,2048]
  short* lpt   = (short*)alloc((size_t)128 * 2048 * 2);     // lo_p^T
  short* prjt  = (short*)alloc((size_t)2048 * 128 * 2);     // proj^T
  short* ot    = (short*)alloc((size_t)2048 * 1024 * 2);    // O^T
  float* biasb = (float*)alloc(2304 * 4);
  float* outf  = (float*)d_out;      // fp32 [16384,2048] for out5
  short* out4b = (short*)d_out;      // bf16 [16384,2048] out4 scratch (dead before O-GEMM writes)

  cast_x_kernel<<<8192, 256, 0, stream>>>(x, x16, (long)Mtot * Dd / 4);
  tcast_kernel<<<dim3(4, 64), dim3(32, 8), 0, stream>>>(Q_w, wbig, 2048, 128);
  tcast_kernel<<<dim3(4, 64), dim3(32, 8), 0, stream>>>(K_w, wbig + 128 * 2048, 2048, 128);
  tcast_kernel<<<dim3(64, 64), dim3(32, 8), 0, stream>>>(lo_proj_w, wbig + 256 * 2048, 2048, 2048);
  tcast_kernel<<<dim3(4, 64), dim3(32, 8), 0, stream>>>(lo_p_w, lpt, 2048, 128);
  tcast_kernel<<<dim3(64, 4), dim3(32, 8), 0, stream>>>(proj_w, prjt, 128, 2048);
  tcast_kernel<<<dim3(64, 32), dim3(32, 8), 0, stream>>>(O_w, ot, 1024, 2048);
  pack_bias_kernel<<<9, 256, 0, stream>>>(Q_b, K_b, lo_proj_b, biasb);

  // [q|k | gelu-hidden] = x @ [Qw|Kw|lo_proj] + bias   (N=2304 merged)
  gemm_tn<3><<<dim3(18, 128), 256, 0, stream>>>(x16, wbig, qk, h16, biasb, Mtot, 2304, 2048);
  // V = h @ lo_p + b
  gemm_tn<0><<<dim3(1, 128), 256, 0, stream>>>(h16, lpt, vbuf, nullptr, lo_p_b, Mtot, 128, 2048);
  // score -> ema (segmented scan)
  ema_kernel<<<dim3(Ss / SEG, 4), 128, 0, stream>>>(qk, emab);
  // mean/clip * V -> x_comb bf16
  comb_kernel<<<Mtot / 4, 256, 0, stream>>>(emab, vbuf, xcomb);
  // out4 = x_comb @ proj + b   (bf16 into d_out scratch)
  gemm_tn<2><<<dim3(16, 128), 256, 0, stream>>>(xcomb, prjt, out4b, nullptr, proj_b, Mtot, 2048, 128);
  // gated = silu(a)*b  -> bf16
  gate_kernel<<<16384, 256, 0, stream>>>(out4b, gated);
  // out5 = gated @ O + b  (fp32 into d_out)
  gemm_tn<0><<<dim3(16, 128), 256, 0, stream>>>(gated, ot, outf, nullptr, O_b, Mtot, 2048, 1024);
  // LN(out5 + x) in place
  ln_kernel<<<Mtot, 256, 0, stream>>>(outf, x, ln_g, ln_b);
}

// Round 3
// 728.696 us; speedup vs baseline: 1.1806x; 1.0285x over previous
//
#include <hip/hip_runtime.h>
#include <cstdint>

#define ALPHA_C 0.15f
#define ONE_MINUS_ALPHA 0.85f
#define CLIP_C 5.0f
#define EPS_C 1e-6f
#define LN_EPS_C 1e-5f

#define Bb 4
#define Ss 4096
#define Dd 2048
#define Mtot (Bb * Ss)  // 16384

typedef __attribute__((ext_vector_type(8))) short bf16x8;
typedef __attribute__((ext_vector_type(4))) float f32x4;

__device__ __forceinline__ short f2bf(float f) {
  union { float f; uint32_t u; } v; v.f = f;
  uint32_t r = v.u + 0x7fffu + ((v.u >> 16) & 1u);  // RNE
  return (short)(r >> 16);
}
__device__ __forceinline__ float sigf(float x) { return 1.0f / (1.0f + __expf(-x)); }
__device__ __forceinline__ float geluf(float x) {
  const float c = 0.7978845608028654f;  // sqrt(2/pi)
  float x3 = x * x * x;
  return 0.5f * x * (1.0f + tanhf(c * (x + 0.044715f * x3)));
}

__device__ __forceinline__ void load_lds16(const short* g, short* l) {
  __builtin_amdgcn_global_load_lds((__attribute__((address_space(1))) void*)g,
                                   (__attribute__((address_space(3))) void*)l, 16, 0, 0);
}

// ---------------- GEMM: C[M,N] = A[M,K](bf16) * Bt[N,K](bf16)^T ----------------
// MODE 0: fp32 out0 = v + bias (ldc).
// MODE 3: merged QK+lo_proj: bx<2 -> score fp32 = sig(a)*sig(b) via lane-pair shfl
//         (Q/K cols interleaved in weights); else out1 bf16 = gelu(v+bias), col-256.
// MODE 4: proj+gate fused: gated bf16 = silu(a)*b via lane-pair shfl (proj cols interleaved).
// MODE 5: fp32 partial = v (no bias), split-K: blockIdx.y = k-chunk, out += y*pstride.
// LDS k-chunk XOR swizzle (R1->R2): fragment ds_read_b128 uniform 2-way (free, m136).
// GROUP-8 bid swizzle: stride-8 blocks (same XCD, round-robin dispatch) share the
// A row-slab sweeping bx -> per-XCD L2 reuse of A.
#define BM 128
#define BN 128
#define BK 32

template <int MODE>
__global__ __launch_bounds__(256, 4) void gemm_tn(
    const short* __restrict__ A, const short* __restrict__ Bt, void* __restrict__ out0,
    void* __restrict__ out1, const float* __restrict__ bias, int K, int lda, int ldb,
    int ldc, int nbx, long pstride) {
  __shared__ __align__(16) short As[BM * BK];
  __shared__ __align__(16) short Bs[BN * BK];

  const int tid = threadIdx.x;
  const int wave = tid >> 6;
  const int lane = tid & 63;
  const int quad = lane >> 4;
  const int l16 = lane & 15;

  const int bid = blockIdx.x;
  const int panel = bid / (8 * nbx);
  const int rem = bid - panel * (8 * nbx);
  const int by = panel * 8 + (rem & 7);
  const int bx = rem >> 3;
  const int m0 = by * BM;
  const int n0 = bx * BN;
  const int wm = (wave & 1) * 64;
  const int wn = (wave >> 1) * 64;

  if (MODE == 5) {  // split-K offset
    A += (long)blockIdx.y * K;
    Bt += (long)blockIdx.y * K;
  }

  // staging: wave stages 32 rows of each tile as two 16-row (1KB) chunks.
  // lane l -> row (l>>2), LDS chunk (l&3); global k-chunk = (l&3) ^ ((l>>3)&3).
  const int srow = wave * 32 + (lane >> 2);
  const int skoff = ((lane & 3) ^ ((lane >> 3) & 3)) * 8;
  const short* agp = A + (long)(m0 + srow) * lda + skoff;
  const short* bgp = Bt + (long)(n0 + srow) * ldb + skoff;
  const short* agp2 = agp + (long)16 * lda;
  const short* bgp2 = bgp + (long)16 * ldb;
  short* al = As + (wave * 32) * BK;
  short* al2 = al + 16 * BK;
  short* bl = Bs + (wave * 32) * BK;
  short* bl2 = bl + 16 * BK;

  const int rsw = (l16 >> 1) & 3;  // read-side swizzle key

  f32x4 acc[4][4] = {};

  for (int k0 = 0; k0 < K; k0 += BK) {
    __syncthreads();
    load_lds16(agp + k0, al);
    load_lds16(agp2 + k0, al2);
    load_lds16(bgp + k0, bl);
    load_lds16(bgp2 + k0, bl2);
    __syncthreads();

    bf16x8 af[4], bfr[4];
#pragma unroll
    for (int i = 0; i < 4; ++i)
      af[i] = *(const bf16x8*)&As[(wm + i * 16 + l16) * BK + (quad ^ rsw) * 8];
#pragma unroll
    for (int j = 0; j < 4; ++j)
      bfr[j] = *(const bf16x8*)&Bs[(wn + j * 16 + l16) * BK + (quad ^ rsw) * 8];
#pragma unroll
    for (int i = 0; i < 4; ++i)
#pragma unroll
      for (int j = 0; j < 4; ++j)
        acc[i][j] = __builtin_amdgcn_mfma_f32_16x16x32_bf16(af[i], bfr[j], acc[i][j], 0, 0, 0);
  }

#pragma unroll
  for (int i = 0; i < 4; ++i) {
#pragma unroll
    for (int r = 0; r < 4; ++r) {
      const int row = m0 + wm + i * 16 + quad * 4 + r;
#pragma unroll
      for (int j = 0; j < 4; ++j) {
        const int col = n0 + wn + j * 16 + l16;
        float v = acc[i][j][r];
        if (MODE != 5) v += bias[col];
        if (MODE == 0) {
          ((float*)out0)[(long)row * ldc + col] = v;
        } else if (MODE == 5) {
          float* o = (float*)out0 + (long)blockIdx.y * pstride;
          o[(long)row * ldc + col] = v;
        } else if (MODE == 3) {
          if (n0 < 256) {  // block-uniform: score region (Q/K interleaved)
            float sh = __shfl_xor(v, 1);
            if (!(lane & 1))
              ((float*)out0)[(long)row * 128 + (col >> 1)] = sigf(v) * sigf(sh);
          } else {
            ((short*)out1)[(long)row * 2048 + (col - 256)] = f2bf(geluf(v));
          }
        } else if (MODE == 4) {  // proj cols interleaved (a_i, b_i)
          float sh = __shfl_xor(v, 1);
          if (!(lane & 1))
            ((short*)out0)[(long)row * 1024 + (col >> 1)] = f2bf(v * sigf(v) * sh);
        }
      }
    }
  }
}

// ---------------- elementwise / prep ----------------
__global__ __launch_bounds__(256) void cast_x_kernel(const float* __restrict__ in,
                                                     short* __restrict__ out, long n4) {
  long i = (long)blockIdx.x * blockDim.x + threadIdx.x;
  const long stride = (long)gridDim.x * blockDim.x;
  for (; i < n4; i += stride) {
    float4 v = ((const float4*)in)[i];
    short4 o;
    o.x = f2bf(v.x); o.y = f2bf(v.y); o.z = f2bf(v.z); o.w = f2bf(v.w);
    ((short4*)out)[i] = o;
  }
}

// in [R,C] fp32 -> out[maprow(c)][r] bf16 (out row length R)
// MAP 0: c; 1: 2c; 2: 2c+1; 3: c<1024 ? 2c : 2(c-1024)+1
template <int MAP>
__global__ __launch_bounds__(256) void tcast_kernel(const float* __restrict__ in,
                                                    short* __restrict__ out, int R, int C) {
  __shared__ float t[32][33];
  const int c0 = blockIdx.x * 32, r0 = blockIdx.y * 32;
  const int tx = threadIdx.x, ty = threadIdx.y;
#pragma unroll
  for (int i = 0; i < 32; i += 8)
    t[ty + i][tx] = in[(long)(r0 + ty + i) * C + (c0 + tx)];
  __syncthreads();
#pragma unroll
  for (int i = 0; i < 32; i += 8) {
    const int c = c0 + ty + i;
    const int orow = (MAP == 0) ? c
                   : (MAP == 1) ? 2 * c
                   : (MAP == 2) ? 2 * c + 1
                                : (c < 1024 ? 2 * c : 2 * (c - 1024) + 1);
    out[(long)orow * R + (r0 + tx)] = f2bf(t[tx][ty + i]);
  }
}

// merged bias: [0,256): interleaved Q_b/K_b; [256,2304): lo_proj_b
__global__ void pack_bias_kernel(const float* __restrict__ qb, const float* __restrict__ kb,
                                 const float* __restrict__ lob, float* __restrict__ o) {
  int i = blockIdx.x * 256 + threadIdx.x;
  if (i < 256) o[i] = (i & 1) ? kb[i >> 1] : qb[i >> 1];
  else if (i < 2304) o[i] = lob[i - 256];
}
// proj bias interleaved (a_i, b_i)
__global__ void pack_pbias_kernel(const float* __restrict__ pjb, float* __restrict__ o) {
  int i = blockIdx.x * 256 + threadIdx.x;
  o[i] = (i & 1) ? pjb[1024 + (i >> 1)] : pjb[i >> 1];
}

// ---------------- EMA over time (input = score fp32 [Mtot,128]) ----------------
// ema[t]=0.15*s[t]+0.85*ema[t-1]; 0.85^96=1.7e-7 warm-up -> independent segments.
#define SEG 64
#define WARM 96
__global__ __launch_bounds__(128) void ema_kernel(const float* __restrict__ score,
                                                  float* __restrict__ ema) {
  const int f = threadIdx.x;
  const int b = blockIdx.y;
  const int seg = blockIdx.x;
  const int t0 = seg * SEG;
  const int tstart = (t0 >= WARM) ? (t0 - WARM) : 0;
  const int tend = t0 + SEG;
  const float* __restrict__ base = score + (long)b * Ss * 128;
  float* __restrict__ eb = ema + (long)b * Ss * 128;

  float e = base[(long)tstart * 128 + f];
  if (seg == 0) eb[f] = e;

  int t = tstart + 1;
  const int CH = 8;
  const int nch = (tend - t) / CH;
  float cur[CH];
#pragma unroll
  for (int i = 0; i < CH; ++i) cur[i] = ALPHA_C * base[(long)(t + i) * 128 + f];
  for (int c = 0; c < nch; ++c) {
    float nxt[CH] = {};
    if (c + 1 < nch) {
#pragma unroll
      for (int i = 0; i < CH; ++i) nxt[i] = ALPHA_C * base[(long)(t + CH + i) * 128 + f];
    }
#pragma unroll
    for (int i = 0; i < CH; ++i) {
      e = fmaf(ONE_MINUS_ALPHA, e, cur[i]);
      const int tt = t + i;
      if (tt >= t0) eb[(long)tt * 128 + f] = e;
    }
#pragma unroll
    for (int i = 0; i < CH; ++i) cur[i] = nxt[i];
    t += CH;
  }
  for (; t < tend; ++t) {
    e = fmaf(ONE_MINUS_ALPHA, e, ALPHA_C * base[(long)t * 128 + f]);
    if (t >= t0) eb[(long)t * 128 + f] = e;
  }
}

// per row: mean over 128 ema, clip(ema/denom), * (sum of 4 V-partials + bias), -> bf16
__global__ __launch_bounds__(256) void comb_kernel(const float* __restrict__ ema,
                                                   const float* __restrict__ vpart,
                                                   const float* __restrict__ lob,
                                                   short* __restrict__ xcomb) {
  const int wv = threadIdx.x >> 6;
  const int lane = threadIdx.x & 63;
  const long row = (long)blockIdx.x * 4 + wv;
  const float* er = ema + row * 128;
  float e0 = er[lane], e1 = er[lane + 64];
  float s = e0 + e1;
#pragma unroll
  for (int m = 1; m < 64; m <<= 1) s += __shfl_xor(s, m, 64);
  const float denom = fmaxf(s * (1.0f / 128.0f), EPS_C);
  const float inv = 1.0f / denom;
  const float c0 = fminf(fmaxf(e0 * inv, -CLIP_C), CLIP_C);
  const float c1 = fminf(fmaxf(e1 * inv, -CLIP_C), CLIP_C);
  const long PS = (long)Mtot * 128;
  float va = lob[lane], vb = lob[lane + 64];
#pragma unroll
  for (int p = 0; p < 4; ++p) {
    va += vpart[p * PS + row * 128 + lane];
    vb += vpart[p * PS + row * 128 + lane + 64];
  }
  xcomb[row * 128 + lane] = f2bf(c0 * va);
  xcomb[row * 128 + 64 + lane] = f2bf(c1 * vb);
}

// in-place: io = LN(io + x) * gamma + beta, row = 2048
__global__ __launch_bounds__(256) void ln_kernel(float* __restrict__ io,
                                                 const float* __restrict__ x,
                                                 const float* __restrict__ gamma,
                                                 const float* __restrict__ beta) {
  const long row = blockIdx.x;
  const int tid = threadIdx.x;
  const int wv = tid >> 6, lane = tid & 63;
  float* rp = io + row * 2048;
  const float* xp = x + row * 2048;
  float4 v0 = ((const float4*)rp)[tid * 2];
  float4 v1 = ((const float4*)rp)[tid * 2 + 1];
  float4 x0 = ((const float4*)xp)[tid * 2];
  float4 x1 = ((const float4*)xp)[tid * 2 + 1];
  float h[8] = {v0.x + x0.x, v0.y + x0.y, v0.z + x0.z, v0.w + x0.w,
                v1.x + x1.x, v1.y + x1.y, v1.z + x1.z, v1.w + x1.w};
  float sum = 0.f, ss = 0.f;
#pragma unroll
  for (int i = 0; i < 8; ++i) { sum += h[i]; ss += h[i] * h[i]; }
#pragma unroll
  for (int m = 1; m < 64; m <<= 1) {
    sum += __shfl_xor(sum, m, 64);
    ss += __shfl_xor(ss, m, 64);
  }
  __shared__ float rs[4], rq[4];
  if (lane == 0) { rs[wv] = sum; rq[wv] = ss; }
  __syncthreads();
  sum = rs[0] + rs[1] + rs[2] + rs[3];
  ss = rq[0] + rq[1] + rq[2] + rq[3];
  const float mu = sum * (1.0f / 2048.0f);
  const float var = ss * (1.0f / 2048.0f) - mu * mu;
  const float rstd = rsqrtf(var + LN_EPS_C);
  const int c0 = tid * 8;
  float o[8];
#pragma unroll
  for (int i = 0; i < 8; ++i)
    o[i] = (h[i] - mu) * rstd * gamma[c0 + i] + beta[c0 + i];
  ((float4*)rp)[tid * 2]     = make_float4(o[0], o[1], o[2], o[3]);
  ((float4*)rp)[tid * 2 + 1] = make_float4(o[4], o[5], o[6], o[7]);
}

// ---------------- launch ----------------
extern "C" void kernel_launch(void* const* d_in, const int* in_sizes, int n_in,
                              void* d_out, int out_size, void* d_ws, size_t ws_size,
                              hipStream_t stream) {
  const float* x         = (const float*)d_in[0];
  const float* Q_w       = (const float*)d_in[1];
  const float* Q_b       = (const float*)d_in[2];
  const float* K_w       = (const float*)d_in[3];
  const float* K_b       = (const float*)d_in[4];
  const float* lo_proj_w = (const float*)d_in[5];
  const float* lo_proj_b = (const float*)d_in[6];
  const float* lo_p_w    = (const float*)d_in[7];
  const float* lo_p_b    = (const float*)d_in[8];
  const float* proj_w    = (const float*)d_in[9];
  const float* proj_b    = (const float*)d_in[10];
  const float* O_w       = (const float*)d_in[11];
  const float* O_b       = (const float*)d_in[12];
  const float* ln_g      = (const float*)d_in[13];
  const float* ln_b      = (const float*)d_in[14];

  char* ws = (char*)d_ws;
  size_t off = 0;
  auto alloc = [&](size_t bytes) {
    char* p = ws + off;
    off += (bytes + 255) & ~(size_t)255;
    return p;
  };
  short* x16   = (short*)alloc((size_t)Mtot * Dd * 2);      // x bf16 (dead after merged GEMM)
  short* h16   = (short*)alloc((size_t)Mtot * Dd * 2);      // gelu hidden bf16
  float* score = (float*)alloc((size_t)Mtot * 128 * 4);     // sig(q)*sig(k) fp32
  float* emab  = (float*)alloc((size_t)Mtot * 128 * 4);     // ema fp32
  short* xcomb = (short*)alloc((size_t)Mtot * 128 * 2);     // bf16
  short* gated = (short*)alloc((size_t)Mtot * 1024 * 2);    // bf16
  short* wbig  = (short*)alloc((size_t)2304 * 2048 * 2);    // [QK-interleaved;lo_proj]^T bf16
  short* lpt   = (short*)alloc((size_t)128 * 2048 * 2);     // lo_p^T
  short* prjt  = (short*)alloc((size_t)2048 * 128 * 2);     // proj^T, (a,b)-interleaved rows
  short* ot    = (short*)alloc((size_t)2048 * 1024 * 2);    // O^T
  float* biasb = (float*)alloc(2304 * 4);
  float* pbias = (float*)alloc(2048 * 4);
  float* vpart = (float*)x16;        // 4 x [Mtot,128] fp32 partials (33.5MB <= 67MB), aliases dead x16
  float* outf  = (float*)d_out;      // fp32 [16384,2048] out5

  cast_x_kernel<<<8192, 256, 0, stream>>>(x, x16, (long)Mtot * Dd / 4);
  tcast_kernel<1><<<dim3(4, 64), dim3(32, 8), 0, stream>>>(Q_w, wbig, 2048, 128);
  tcast_kernel<2><<<dim3(4, 64), dim3(32, 8), 0, stream>>>(K_w, wbig, 2048, 128);
  tcast_kernel<0><<<dim3(64, 64), dim3(32, 8), 0, stream>>>(lo_proj_w, wbig + 256 * 2048, 2048, 2048);
  tcast_kernel<0><<<dim3(4, 64), dim3(32, 8), 0, stream>>>(lo_p_w, lpt, 2048, 128);
  tcast_kernel<3><<<dim3(64, 4), dim3(32, 8), 0, stream>>>(proj_w, prjt, 128, 2048);
  tcast_kernel<0><<<dim3(64, 32), dim3(32, 8), 0, stream>>>(O_w, ot, 1024, 2048);
  pack_bias_kernel<<<9, 256, 0, stream>>>(Q_b, K_b, lo_proj_b, biasb);
  pack_pbias_kernel<<<8, 256, 0, stream>>>(proj_b, pbias);

  // [score | gelu-hidden] = x @ [QK-ilv | lo_proj] + bias   (N=2304 merged)
  gemm_tn<3><<<18 * 128, 256, 0, stream>>>(x16, wbig, score, h16, biasb,
                                           2048, 2048, 2048, 0, 18, 0);
  // ema over time (segmented scan)
  ema_kernel<<<dim3(Ss / SEG, 4), 128, 0, stream>>>(score, emab);
  // V partials = h @ lo_p (split-K x4; x16 is dead, vpart aliases it)
  gemm_tn<5><<<dim3(128, 4), 256, 0, stream>>>(h16, lpt, vpart, nullptr, nullptr,
                                               512, 2048, 2048, 128, 1, (long)Mtot * 128);
  // mean/clip * (sum V partials + bias) -> x_comb bf16
  comb_kernel<<<Mtot / 4, 256, 0, stream>>>(emab, vpart, lo_p_b, xcomb);
  // gated = silu(a)*b fused into proj GEMM (interleaved cols)
  gemm_tn<4><<<16 * 128, 256, 0, stream>>>(xcomb, prjt, gated, nullptr, pbias,
                                           128, 128, 128, 1024, 16, 0);
  // out5 = gated @ O + b  (fp32 into d_out)
  gemm_tn<0><<<16 * 128, 256, 0, stream>>>(gated, ot, outf, nullptr, O_b,
                                           1024, 1024, 1024, 2048, 16, 0);
  // LN(out5 + x) in place
  ln_kernel<<<Mtot, 256, 0, stream>>>(outf, x, ln_g, ln_b);
}